// Round 1
// baseline (753.740 us; speedup 1.0000x reference)
//
#include <hip/hip_runtime.h>
#include <math.h>

#define N_NODES 100000

// ---------------- GEMM: C[N,M] = A[N,K] * B[K,M], row-major ----------------
// M % 64 == 0, K % 16 == 0. Block 256 threads, 64x64 tile, 4x4 per thread.
__global__ __launch_bounds__(256) void gemm_kernel(const float* __restrict__ A,
                                                   const float* __restrict__ B,
                                                   float* __restrict__ C,
                                                   int n, int k, int m) {
    __shared__ float As[16][68];
    __shared__ float Bs[16][68];
    const int row0 = blockIdx.x * 64;
    const int col0 = blockIdx.y * 64;
    const int tid = threadIdx.x;
    const int tr = tid >> 4;   // 0..15
    const int tc = tid & 15;   // 0..15
    float acc[4][4] = {};
    for (int k0 = 0; k0 < k; k0 += 16) {
        // load A tile 64x16: lane -> (m = tid>>4 (+16*i), kk = tid&15)
        {
            const int kk = tid & 15;
            const int mbase = tid >> 4;
#pragma unroll
            for (int i = 0; i < 4; ++i) {
                const int mm = mbase + i * 16;
                const int row = row0 + mm;
                As[kk][mm] = (row < n) ? A[(size_t)row * k + k0 + kk] : 0.f;
            }
        }
        // load B tile 16x64: lane -> (kk = tid>>6 (+4*i), nn = tid&63)
        {
            const int nn = tid & 63;
            const int kbase = tid >> 6;
#pragma unroll
            for (int i = 0; i < 4; ++i) {
                const int kk = kbase + i * 4;
                Bs[kk][nn] = B[(size_t)(k0 + kk) * m + col0 + nn];
            }
        }
        __syncthreads();
#pragma unroll
        for (int kk = 0; kk < 16; ++kk) {
            float a[4], b[4];
#pragma unroll
            for (int i = 0; i < 4; ++i) a[i] = As[kk][tr * 4 + i];
#pragma unroll
            for (int j = 0; j < 4; ++j) b[j] = Bs[kk][tc * 4 + j];
#pragma unroll
            for (int i = 0; i < 4; ++i)
#pragma unroll
                for (int j = 0; j < 4; ++j) acc[i][j] += a[i] * b[j];
        }
        __syncthreads();
    }
#pragma unroll
    for (int i = 0; i < 4; ++i) {
        const int row = row0 + tr * 4 + i;
        if (row < n) {
#pragma unroll
            for (int j = 0; j < 4; ++j)
                C[(size_t)row * m + col0 + tc * 4 + j] = acc[i][j];
        }
    }
}

// ------------- per-node attention coefficients a_src, a_dst ---------------
template <int H, int C>
__global__ void att_kernel(const float* __restrict__ h,
                           const float* __restrict__ att_s,
                           const float* __restrict__ att_d,
                           float* __restrict__ as_, float* __restrict__ ad_,
                           int n) {
    const int idx = blockIdx.x * blockDim.x + threadIdx.x;
    if (idx >= n * H) return;
    const int node = idx / H;
    const int hh = idx % H;
    const float* hp = h + (size_t)node * H * C + hh * C;
    float s0 = 0.f, s1 = 0.f;
#pragma unroll
    for (int c = 0; c < C; ++c) {
        const float v = hp[c];
        s0 += v * att_s[hh * C + c];
        s1 += v * att_d[hh * C + c];
    }
    as_[idx] = s0;
    ad_[idx] = s1;
}

// ----------------------------- CSR build ----------------------------------
__global__ void deg_kernel(const int* __restrict__ dst, int* __restrict__ deg,
                           int e) {
    const int i = blockIdx.x * blockDim.x + threadIdx.x;
    if (i < e) atomicAdd(&deg[dst[i]], 1);
}

__global__ __launch_bounds__(1024) void scan1_kernel(const int* __restrict__ deg,
                                                     int* __restrict__ offs,
                                                     int* __restrict__ sums,
                                                     int n) {
    __shared__ int s[1024];
    const int t = threadIdx.x;
    const int i = blockIdx.x * 1024 + t;
    const int v = (i < n) ? deg[i] : 0;
    s[t] = v;
    __syncthreads();
    for (int d = 1; d < 1024; d <<= 1) {
        const int x = (t >= d) ? s[t - d] : 0;
        __syncthreads();
        s[t] += x;
        __syncthreads();
    }
    if (i < n) offs[i] = s[t] - v;  // exclusive
    if (t == 1023) sums[blockIdx.x] = s[1023];
}

__global__ __launch_bounds__(128) void scan2_kernel(int* sums, int nb) {
    __shared__ int s[128];
    const int t = threadIdx.x;
    const int v = (t < nb) ? sums[t] : 0;
    s[t] = v;
    __syncthreads();
    for (int d = 1; d < 128; d <<= 1) {
        const int x = (t >= d) ? s[t - d] : 0;
        __syncthreads();
        s[t] += x;
        __syncthreads();
    }
    if (t < nb) sums[t] = s[t] - v;  // exclusive over block totals
}

__global__ __launch_bounds__(1024) void scan3_kernel(int* __restrict__ offs,
                                                     const int* __restrict__ sums,
                                                     int* __restrict__ cursor,
                                                     int n) {
    const int i = blockIdx.x * 1024 + threadIdx.x;
    if (i < n) {
        const int o = offs[i] + sums[blockIdx.x];
        offs[i] = o;
        cursor[i] = o;
    }
}

__global__ void fill_kernel(const int* __restrict__ src,
                            const int* __restrict__ dst, int* cursor,
                            int* __restrict__ csr, int e) {
    const int i = blockIdx.x * blockDim.x + threadIdx.x;
    if (i < e) {
        const int p = atomicAdd(&cursor[dst[i]], 1);
        csr[p] = src[i];
    }
}

// --------- per-dst online-softmax gather-aggregate (one wave/node) --------
template <int H, int C, bool DO_ELU>
__global__ __launch_bounds__(64) void agg_kernel(
    const float* __restrict__ h, const float* __restrict__ a_src,
    const float* __restrict__ a_dst, const int* __restrict__ csr,
    const int* __restrict__ offs, const int* __restrict__ deg,
    const float* __restrict__ bias, float* __restrict__ out, int n) {
    constexpr int HC = H * C;
    constexpr int R = HC / 64;  // values per lane
    const int dst = blockIdx.x;
    const int lane = threadIdx.x;

    float acc[R], m[R], l[R], adv[R];
    int hh[R];
#pragma unroll
    for (int r = 0; r < R; ++r) {
        acc[r] = 0.f;
        l[r] = 0.f;
        m[r] = -1e30f;
        hh[r] = (lane + 64 * r) / C;
        adv[r] = a_dst[dst * H + hh[r]];
    }
    const int start = offs[dst];
    const int d = deg[dst];
    for (int j = 0; j <= d; ++j) {  // j==d is the self loop
        const int src = (j < d) ? csr[start + j] : dst;
#pragma unroll
        for (int r = 0; r < R; ++r) {
            float e = a_src[src * H + hh[r]] + adv[r];
            e = (e >= 0.f) ? e : 0.2f * e;  // LeakyReLU(0.2)
            const float hv = h[(size_t)src * HC + lane + 64 * r];
            const float mn = fmaxf(m[r], e);
            const float sc = __expf(m[r] - mn);
            const float p = __expf(e - mn);
            acc[r] = acc[r] * sc + p * hv;
            l[r] = l[r] * sc + p;
            m[r] = mn;
        }
    }
#pragma unroll
    for (int r = 0; r < R; ++r) {
        const int v = lane + 64 * r;
        float res = acc[r] / (l[r] + 1e-16f) + bias[v];
        if (DO_ELU) res = (res > 0.f) ? res : (__expf(res) - 1.f);
        out[(size_t)dst * HC + v] = res;
    }
}

// --------------------------------------------------------------------------
extern "C" void kernel_launch(void* const* d_in, const int* in_sizes, int n_in,
                              void* d_out, int out_size, void* d_ws,
                              size_t ws_size, hipStream_t stream) {
    const float* x = (const float*)d_in[0];
    const int* ei = (const int*)d_in[1];
    const float* W1 = (const float*)d_in[2];
    const float* att_s1 = (const float*)d_in[3];
    const float* att_d1 = (const float*)d_in[4];
    const float* b1 = (const float*)d_in[5];
    const float* W2 = (const float*)d_in[6];
    const float* att_s2 = (const float*)d_in[7];
    const float* att_d2 = (const float*)d_in[8];
    const float* b2 = (const float*)d_in[9];

    const int N = in_sizes[0] / 256;   // 100000
    const int E = in_sizes[1] / 2;     // 1600000
    const int* srcp = ei;
    const int* dstp = ei + E;

    // workspace layout (floats/ints, 4B each)
    float* h1 = (float*)d_ws;          // N*128
    float* h1p = h1 + (size_t)N * 128; // N*128
    float* as1 = h1p + (size_t)N * 128;  // N*4
    float* ad1 = as1 + (size_t)N * 4;    // N*4
    float* as2 = ad1 + (size_t)N * 4;    // N
    float* ad2 = as2 + N;                // N
    int* deg = (int*)(ad2 + N);          // N
    int* offs = deg + N;                 // N
    int* cursor = offs + N;              // N
    int* sums = cursor + N;              // 128
    int* csr = sums + 128;               // E
    float* h2 = h1;  // alias: h1 dead after layer-1 aggregation

    const int nb = (N + 1023) / 1024;  // 98 scan blocks

    // ---- CSR build ----
    hipMemsetAsync(deg, 0, (size_t)N * 4, stream);
    deg_kernel<<<(E + 255) / 256, 256, 0, stream>>>(dstp, deg, E);
    scan1_kernel<<<nb, 1024, 0, stream>>>(deg, offs, sums, N);
    scan2_kernel<<<1, 128, 0, stream>>>(sums, nb);
    scan3_kernel<<<nb, 1024, 0, stream>>>(offs, sums, cursor, N);
    fill_kernel<<<(E + 255) / 256, 256, 0, stream>>>(srcp, dstp, cursor, csr, E);

    // ---- layer 1 ----
    {
        dim3 grid((N + 63) / 64, 128 / 64);
        gemm_kernel<<<grid, 256, 0, stream>>>(x, W1, h1, N, 256, 128);
    }
    att_kernel<4, 32><<<(N * 4 + 255) / 256, 256, 0, stream>>>(h1, att_s1,
                                                               att_d1, as1,
                                                               ad1, N);
    agg_kernel<4, 32, true><<<N, 64, 0, stream>>>(h1, as1, ad1, csr, offs, deg,
                                                  b1, h1p, N);

    // ---- layer 2 ----
    {
        dim3 grid((N + 63) / 64, 64 / 64);
        gemm_kernel<<<grid, 256, 0, stream>>>(h1p, W2, h2, N, 128, 64);
    }
    att_kernel<1, 64><<<(N + 255) / 256, 256, 0, stream>>>(h2, att_s2, att_d2,
                                                           as2, ad2, N);
    agg_kernel<1, 64, false><<<N, 64, 0, stream>>>(h2, as2, ad2, csr, offs,
                                                   deg, b2, (float*)d_out, N);
}